// Round 1
// baseline (183.042 us; speedup 1.0000x reference)
//
#include <hip/hip_runtime.h>

#define BLOCK   256
#define B_ROWS  131072
#define C_COLS  128
#define K_SEL   64
#define ROWS_PER_BLOCK 64
#define GRID    (B_ROWS / ROWS_PER_BLOCK)   // 2048 blocks
#define F4_PER_ROW (C_COLS / 4)             // 32 float4 per row

__device__ __forceinline__ float fast_log(float x) {
    return __log2f(x) * 0.6931471805599453f;   // v_log_f32 + mul
}

__device__ __forceinline__ float per_elem_loss(float o, float oc, float y,
                                               float wc) {
    float sharp = (o > 0.5f) ? (o + (1.0f - o) * 0.25f)
                             : (o * 0.75f);
    float lo  = fmaxf(fast_log(o),        -100.0f);
    float l1o = fmaxf(fast_log(1.0f - o), -100.0f);
    float bce = -(y * lo + (1.0f - y) * l1o);
    float dp = o  - sharp;
    float dc = oc - sharp;
    return wc * (bce + dp * dp + dc * dc);
}

// One kernel does: per-block weight table (w[c] = multiplicity of column c in
// class_idx), ballot-compaction of the 64 rows this block owns, then an
// unconditional fully-coalesced float4 stream over active rows only.
__global__ __launch_bounds__(BLOCK) void semi_loss_main(
    const float* __restrict__ out,
    const float* __restrict__ outc,
    const float* __restrict__ lab,
    const int*  __restrict__ class_idx,
    const int*  __restrict__ batch_mask,
    float2* __restrict__ partials)
{
    __shared__ __align__(16) float sw[C_COLS];
    __shared__ int   slist[ROWS_PER_BLOCK];
    __shared__ int   snact;

    const int row0 = blockIdx.x * ROWS_PER_BLOCK;
    const int tid  = threadIdx.x;

    if (tid < 64) {
        // wave 0: mask ballot + compacted active-row list
        int m = (batch_mask[row0 + tid] != 0) ? 1 : 0;
        unsigned long long bal = __ballot(m);
        if (m) {
            int pos = __popcll(bal & ((1ull << tid) - 1ull));
            slist[pos] = tid;
        }
        if (tid == 0) snact = (int)__popcll(bal);
    } else if (tid < 192) {
        // waves 1-2: column weight table (class_idx is 64 ints, L2-hot)
        int c = tid - 64;
        int cnt = 0;
        #pragma unroll
        for (int k = 0; k < K_SEL; ++k)
            cnt += (class_idx[k] == c) ? 1 : 0;
        sw[c] = (float)cnt;
    }
    __syncthreads();

    const int   c4  = tid & 31;          // float4 column slot (0..31)
    const int   sub = tid >> 5;          // row-slot within 8-row group
    const float4 w4 = ((const float4*)sw)[c4];
    const int   nact = snact;

    float sum = 0.0f;
    for (int j = sub; j < nact; j += 8) {
        const int v = (row0 + slist[j]) * F4_PER_ROW + c4;
        float4 o4  = ((const float4*)out )[v];
        float4 oc4 = ((const float4*)outc)[v];
        float4 y4  = ((const float4*)lab )[v];
        sum += per_elem_loss(o4.x, oc4.x, y4.x, w4.x)
             + per_elem_loss(o4.y, oc4.y, y4.y, w4.y)
             + per_elem_loss(o4.z, oc4.z, y4.z, w4.z)
             + per_elem_loss(o4.w, oc4.w, y4.w, w4.w);
    }

    // wave (64) shuffle reduction, then LDS across the block's 4 waves
    #pragma unroll
    for (int off = 32; off > 0; off >>= 1)
        sum += __shfl_down(sum, off);

    __shared__ float ssum[BLOCK / 64];
    int wave = tid >> 6;
    int lane = tid & 63;
    if (lane == 0) ssum[wave] = sum;
    __syncthreads();
    if (tid == 0) {
        float s = 0.0f;
        #pragma unroll
        for (int i = 0; i < BLOCK / 64; ++i) s += ssum[i];
        partials[blockIdx.x] = make_float2(s, (float)nact);
    }
}

__global__ __launch_bounds__(BLOCK) void semi_loss_reduce(
    const float2* __restrict__ partials, float* __restrict__ out)
{
    double s = 0.0, c = 0.0;
    for (int i = threadIdx.x; i < GRID; i += BLOCK) {
        float2 p = partials[i];
        s += (double)p.x;
        c += (double)p.y;
    }
    #pragma unroll
    for (int off = 32; off > 0; off >>= 1) {
        s += __shfl_down(s, off);
        c += __shfl_down(c, off);
    }
    __shared__ double dsum[BLOCK / 64];
    __shared__ double dcnt[BLOCK / 64];
    int wave = threadIdx.x >> 6;
    int lane = threadIdx.x & 63;
    if (lane == 0) { dsum[wave] = s; dcnt[wave] = c; }
    __syncthreads();
    if (threadIdx.x == 0) {
        double ts = 0.0, tc = 0.0;
        #pragma unroll
        for (int i = 0; i < BLOCK / 64; ++i) { ts += dsum[i]; tc += dcnt[i]; }
        out[0] = (float)(ts / (tc * (double)K_SEL));
    }
}

extern "C" void kernel_launch(void* const* d_in, const int* in_sizes, int n_in,
                              void* d_out, int out_size, void* d_ws, size_t ws_size,
                              hipStream_t stream) {
    const float* out_p  = (const float*)d_in[0];
    const float* outc_p = (const float*)d_in[1];
    const float* lab_p  = (const float*)d_in[2];
    const int*   cidx_p = (const int*)d_in[3];
    const int*   mask_p = (const int*)d_in[4];

    float2* partials = (float2*)d_ws;   // GRID * 8 B = 16 KB

    semi_loss_main<<<GRID, BLOCK, 0, stream>>>(out_p, outc_p, lab_p,
                                               cidx_p, mask_p, partials);
    semi_loss_reduce<<<1, BLOCK, 0, stream>>>(partials, (float*)d_out);
}

// Round 2
// 167.893 us; speedup vs baseline: 1.0902x; 1.0902x over previous
//
#include <hip/hip_runtime.h>

#define BLOCK   256
#define B_ROWS  131072
#define C_COLS  128
#define K_SEL   64
#define ROWS_PER_BLOCK 64
#define GRID    (B_ROWS / ROWS_PER_BLOCK)   // 2048 blocks
#define F4_PER_ROW (C_COLS / 4)             // 32 float4 per row

typedef float f4v __attribute__((ext_vector_type(4)));

__device__ __forceinline__ f4v ntld(const f4v* __restrict__ p) {
    return __builtin_nontemporal_load(p);   // global_load_dwordx4 nt
}

__device__ __forceinline__ float fast_log(float x) {
    return __log2f(x) * 0.6931471805599453f;   // v_log_f32 + mul
}

__device__ __forceinline__ float per_elem_loss(float o, float oc, float y,
                                               float wc) {
    float sharp = (o > 0.5f) ? (o + (1.0f - o) * 0.25f)
                             : (o * 0.75f);
    float lo  = fmaxf(fast_log(o),        -100.0f);
    float l1o = fmaxf(fast_log(1.0f - o), -100.0f);
    float bce = -(y * lo + (1.0f - y) * l1o);
    float dp = o  - sharp;
    float dc = oc - sharp;
    return wc * (bce + dp * dp + dc * dc);
}

__device__ __forceinline__ float quad(f4v o, f4v oc, f4v y, f4v w) {
    return per_elem_loss(o.x, oc.x, y.x, w.x)
         + per_elem_loss(o.y, oc.y, y.y, w.y)
         + per_elem_loss(o.z, oc.z, y.z, w.z)
         + per_elem_loss(o.w, oc.w, y.w, w.w);
}

// Per-block: weight table (w[c] = multiplicity of column c in class_idx),
// ballot-compaction of the block's 64 rows, then a 2-deep software-pipelined
// non-temporal float4 stream over active rows only.
__global__ __launch_bounds__(BLOCK) void semi_loss_main(
    const float* __restrict__ out,
    const float* __restrict__ outc,
    const float* __restrict__ lab,
    const int*  __restrict__ class_idx,
    const int*  __restrict__ batch_mask,
    float2* __restrict__ partials)
{
    __shared__ __align__(16) float sw[C_COLS];
    __shared__ int   slist[ROWS_PER_BLOCK];
    __shared__ int   snact;

    const int row0 = blockIdx.x * ROWS_PER_BLOCK;
    const int tid  = threadIdx.x;

    if (tid < 64) {
        // wave 0: mask ballot + compacted active-row list
        int m = (batch_mask[row0 + tid] != 0) ? 1 : 0;
        unsigned long long bal = __ballot(m);
        if (m) {
            int pos = __popcll(bal & ((1ull << tid) - 1ull));
            slist[pos] = tid;
        }
        if (tid == 0) snact = (int)__popcll(bal);
    } else if (tid < 192) {
        // waves 1-2: column weight table (class_idx is 64 ints, L2-hot)
        int c = tid - 64;
        int cnt = 0;
        #pragma unroll
        for (int k = 0; k < K_SEL; ++k)
            cnt += (class_idx[k] == c) ? 1 : 0;
        sw[c] = (float)cnt;
    }
    __syncthreads();

    const int   c4  = tid & 31;          // float4 column slot (0..31)
    const int   sub = tid >> 5;          // row-slot within 8-row group
    const f4v   w4  = ((const f4v*)sw)[c4];
    const int   nact = snact;

    const f4v* __restrict__ po  = (const f4v*)out;
    const f4v* __restrict__ poc = (const f4v*)outc;
    const f4v* __restrict__ py  = (const f4v*)lab;

    float sum = 0.0f;
    int j = sub;
    if (j < nact) {
        // prologue: issue stage-A loads
        int v = (row0 + slist[j]) * F4_PER_ROW + c4;
        f4v o4  = ntld(po  + v);
        f4v oc4 = ntld(poc + v);
        f4v y4  = ntld(py  + v);
        j += 8;
        while (j < nact) {
            // issue stage-B loads BEFORE consuming stage A: compiler can
            // wait vmcnt(3) for A while B stays in flight.
            int v2 = (row0 + slist[j]) * F4_PER_ROW + c4;
            f4v o4n  = ntld(po  + v2);
            f4v oc4n = ntld(poc + v2);
            f4v y4n  = ntld(py  + v2);
            sum += quad(o4, oc4, y4, w4);
            o4 = o4n; oc4 = oc4n; y4 = y4n;
            j += 8;
        }
        sum += quad(o4, oc4, y4, w4);
    }

    // wave (64) shuffle reduction, then LDS across the block's 4 waves
    float cntf = (tid == 0) ? (float)nact : 0.0f;
    #pragma unroll
    for (int off = 32; off > 0; off >>= 1)
        sum += __shfl_down(sum, off);

    __shared__ float ssum[BLOCK / 64];
    int wave = tid >> 6;
    int lane = tid & 63;
    if (lane == 0) ssum[wave] = sum;
    __syncthreads();
    if (tid == 0) {
        float s = 0.0f;
        #pragma unroll
        for (int i = 0; i < BLOCK / 64; ++i) s += ssum[i];
        partials[blockIdx.x] = make_float2(s, cntf);
    }
}

__global__ __launch_bounds__(BLOCK) void semi_loss_reduce(
    const float2* __restrict__ partials, float* __restrict__ out)
{
    double s = 0.0, c = 0.0;
    for (int i = threadIdx.x; i < GRID; i += BLOCK) {
        float2 p = partials[i];
        s += (double)p.x;
        c += (double)p.y;
    }
    #pragma unroll
    for (int off = 32; off > 0; off >>= 1) {
        s += __shfl_down(s, off);
        c += __shfl_down(c, off);
    }
    __shared__ double dsum[BLOCK / 64];
    __shared__ double dcnt[BLOCK / 64];
    int wave = threadIdx.x >> 6;
    int lane = threadIdx.x & 63;
    if (lane == 0) { dsum[wave] = s; dcnt[wave] = c; }
    __syncthreads();
    if (threadIdx.x == 0) {
        double ts = 0.0, tc = 0.0;
        #pragma unroll
        for (int i = 0; i < BLOCK / 64; ++i) { ts += dsum[i]; tc += dcnt[i]; }
        out[0] = (float)(ts / (tc * (double)K_SEL));
    }
}

extern "C" void kernel_launch(void* const* d_in, const int* in_sizes, int n_in,
                              void* d_out, int out_size, void* d_ws, size_t ws_size,
                              hipStream_t stream) {
    const float* out_p  = (const float*)d_in[0];
    const float* outc_p = (const float*)d_in[1];
    const float* lab_p  = (const float*)d_in[2];
    const int*   cidx_p = (const int*)d_in[3];
    const int*   mask_p = (const int*)d_in[4];

    float2* partials = (float2*)d_ws;   // GRID * 8 B = 16 KB

    semi_loss_main<<<GRID, BLOCK, 0, stream>>>(out_p, outc_p, lab_p,
                                               cidx_p, mask_p, partials);
    semi_loss_reduce<<<1, BLOCK, 0, stream>>>(partials, (float*)d_out);
}